// Round 1
// 119.984 us; speedup vs baseline: 1.0085x; 1.0085x over previous
//
#include <hip/hip_runtime.h>

#define BB 4
#define TT 1024
#define DD 1024
#define UU 64
#define HW 32   // WIDTH/2

typedef unsigned short u16;
typedef __attribute__((ext_vector_type(4))) unsigned short u16x4;
typedef __attribute__((ext_vector_type(8))) unsigned short u16x8;
typedef __attribute__((ext_vector_type(8))) short bf16x8;   // raw bf16 bit patterns
typedef __attribute__((ext_vector_type(4))) float f32x4;

// round-to-nearest-even fp32 -> bf16 (inputs are finite randn; no NaN handling)
__device__ __forceinline__ u16 bf16_rne(float f) {
  unsigned b = __builtin_bit_cast(unsigned, f);
  b += 0x7FFFu + ((b >> 16) & 1u);
  return (u16)(b >> 16);
}
__device__ __forceinline__ float bf16_tof(u16 h) {
  return __builtin_bit_cast(float, ((unsigned)h) << 16);
}

// tanh via hw exp: tanh(|x|) = (1 - e^{-2|x|}) / (1 + e^{-2|x|}), no overflow, ~1e-6 abs err
__device__ __forceinline__ float tanh_fast(float x) {
  float ax = __builtin_fabsf(x);
  float t = __expf(-2.0f * ax);                     // (0, 1]
  float r = (1.0f - t) * __builtin_amdgcn_rcpf(1.0f + t);
  return __builtin_copysignf(r, x);
}

// ---------------------------------------------------------------------------
// wprep: W = [Wt | Wx] fp32 [1024 d][128 u]  ->  transposed bf16 hi/lo
//        Wht/Wlt [128 u][1024 k], k-contiguous so MFMA B-fragments are single
//        16 B loads. 512 KB total, L2-resident for proj. Split: w = hi + lo,
//        hi = bf16_rne(w) (|lo| <= 2^-9|w|), lo = bf16_rne(w - hi).
// ---------------------------------------------------------------------------
__global__ __launch_bounds__(128) void wprep_kernel(
    const float* __restrict__ Wt, const float* __restrict__ Wx,
    u16* __restrict__ Wht, u16* __restrict__ Wlt)
{
  const int u = blockIdx.x;            // 0..127 (u<64 -> Wt col, else Wx col)
  const int c = threadIdx.x;           // 0..127 -> k = 8c..8c+7
  const float* src = (u < UU) ? (Wt + u) : (Wx + (u - UU));
  u16x8 h, l;
  #pragma unroll
  for (int j = 0; j < 8; ++j) {
    float v = src[(size_t)(8 * c + j) * UU];
    u16 hh = bf16_rne(v);
    float lf = v - bf16_tof(hh);       // exact (Sterbenz)
    h[j] = hh;
    l[j] = bf16_rne(lf);
  }
  *(u16x8*)(Wht + (size_t)u * DD + 8 * c) = h;
  *(u16x8*)(Wlt + (size_t)u * DD + 8 * c) = l;
}

// ---------------------------------------------------------------------------
// proj via bf16-split MFMA: q|k [4096][64] = X[4096][1024] @ [Wt|Wx][1024][128]
// fp32-accurate via x = xh + xl (RNE split): acc = xh*wh + xh*wl + xl*wh + xl*wl
// (all 4 terms kept; residual error ~2^-18 relative, ~1e-5 abs on q).
// 256 blocks x 16 rows; 8 waves, wave w owns 16-col fragment u0=16w.
// X-tile staged once in LDS as bf16 h/l (row stride 1032 -> 2-way max aliasing).
// mfma_f32_16x16x32_bf16 layouts:
//   A: lane holds row (l&15), k = 8*(l>>4)+j (contiguous -> ds_read_b128)
//   B: lane holds col (l&15), k = 8*(l>>4)+j (contiguous from W^T -> dwordx4)
//   D: lane l reg r -> row 4*(l>>4)+r, col l&15  [m89-verified]
// ---------------------------------------------------------------------------
#define PROWS 16
#define XLD (DD + 8)    // 1032 bf16 row stride: 2064 B -> bank base 4*(r+g), 2-way max

__global__ __launch_bounds__(512) void proj_mfma_kernel(
    const float* __restrict__ x, const u16* __restrict__ Wht,
    const u16* __restrict__ Wlt, float* __restrict__ qo, float* __restrict__ ko)
{
  __shared__ __align__(16) u16 Xh[PROWS][XLD];   // 33 KB
  __shared__ __align__(16) u16 Xl[PROWS][XLD];   // 33 KB

  const int tid  = threadIdx.x;
  const int row0 = blockIdx.x * PROWS;

  // ---- stage 16 rows of x, converting fp32 -> bf16 hi/lo ----
  {
    const float4* src = (const float4*)(x + (size_t)row0 * DD);
    #pragma unroll
    for (int i = 0; i < 8; ++i) {
      int idx4 = tid + 512 * i;            // 0..4095 float4s
      int r    = idx4 >> 8;                // row 0..15
      int k4   = (idx4 & 255) << 2;        // k offset in floats
      float4 v = src[idx4];
      float vv[4] = {v.x, v.y, v.z, v.w};
      u16x4 hv, lv;
      #pragma unroll
      for (int j = 0; j < 4; ++j) {
        u16 hh = bf16_rne(vv[j]);
        float lf = vv[j] - bf16_tof(hh);
        hv[j] = hh;
        lv[j] = bf16_rne(lf);
      }
      *(u16x4*)&Xh[r][k4] = hv;
      *(u16x4*)&Xl[r][k4] = lv;
    }
  }
  __syncthreads();

  const int lane = tid & 63;
  const int wv   = tid >> 6;          // wave 0..7 -> col fragment
  const int arow = lane & 15;         // A row / B col / D col
  const int g    = lane >> 4;         // k-octet group 0..3
  const int u0   = wv * 16;

  const u16* ah_p = &Xh[arow][8 * g];
  const u16* al_p = &Xl[arow][8 * g];
  const u16* bh_p = Wht + (size_t)(u0 + arow) * DD + 8 * g;
  const u16* bl_p = Wlt + (size_t)(u0 + arow) * DD + 8 * g;

  f32x4 acc0 = {0.f, 0.f, 0.f, 0.f};
  f32x4 acc1 = {0.f, 0.f, 0.f, 0.f};
  f32x4 acc2 = {0.f, 0.f, 0.f, 0.f};
  f32x4 acc3 = {0.f, 0.f, 0.f, 0.f};

  #pragma unroll 8
  for (int ks = 0; ks < 32; ++ks) {
    bf16x8 ah = *(const bf16x8*)(ah_p + 32 * ks);
    bf16x8 al = *(const bf16x8*)(al_p + 32 * ks);
    bf16x8 bh = *(const bf16x8*)(bh_p + 32 * ks);
    bf16x8 bl = *(const bf16x8*)(bl_p + 32 * ks);
    acc0 = __builtin_amdgcn_mfma_f32_16x16x32_bf16(ah, bh, acc0, 0, 0, 0);
    acc1 = __builtin_amdgcn_mfma_f32_16x16x32_bf16(ah, bl, acc1, 0, 0, 0);
    acc2 = __builtin_amdgcn_mfma_f32_16x16x32_bf16(al, bh, acc2, 0, 0, 0);
    acc3 = __builtin_amdgcn_mfma_f32_16x16x32_bf16(al, bl, acc3, 0, 0, 0);
  }

  // D: lane l, reg r -> row 4*g + r, col u0 + arow; cols 0-63 -> q, 64-127 -> k
  const int col = u0 + arow;
  float* dst = (col < UU) ? (qo + col) : (ko + (col - UU));
  #pragma unroll
  for (int r = 0; r < 4; ++r) {
    dst[(size_t)(row0 + 4 * g + r) * UU] = acc0[r] + acc1[r] + acc2[r] + acc3[r];
  }
}

// ---------------------------------------------------------------------------
// band: UNCHANGED from baseline (isolates the proj delta this round).
// per block, 8 query rows (i0..i0+7) of batch b; NJ<=71 key rows.
// ---------------------------------------------------------------------------
__global__ __launch_bounds__(512) void band_kernel(
    const float* __restrict__ x,  const float* __restrict__ qi,
    const float* __restrict__ ki, const float* __restrict__ bh,
    const float* __restrict__ Wa, const float* __restrict__ ba,
    float* __restrict__ out)
{
  __shared__ __align__(16) float qpb[8 * UU];    // q + bh
  __shared__ __align__(16) float ks[72 * UU];    // 18 KB
  __shared__ __align__(16) float at[72 * 8];     // scores / weights, [j][i]

  const int tid  = threadIdx.x;
  const int bid  = blockIdx.x;
  const int tile = (bid & 7) * 64 + (bid >> 3);  // XCD-locality swizzle (512 = 8*64)
  const int b    = tile >> 7;
  const int i0   = (tile & 127) * 8;

  const int jlo = max(0, i0 - HW);
  const int jhi = min(TT, i0 + 8 - 1 + HW);      // exclusive
  const int NJ  = jhi - jlo;                     // 39..71

  // ---- stage q(+bh), k ----
  {
    if (tid < 128) {
      float4 qv = ((const float4*)(qi + (size_t)(b * TT + i0) * UU))[tid];
      float4 bv = ((const float4*)bh)[tid & 15];
      qv.x += bv.x; qv.y += bv.y; qv.z += bv.z; qv.w += bv.w;
      ((float4*)qpb)[tid] = qv;
    }
    const float4* ksrc = (const float4*)(ki + (size_t)(b * TT + jlo) * UU);
    float4* kdst = (float4*)ks;
    const int nk4 = NJ * (UU / 4);
    for (int i2 = tid; i2 < nk4; i2 += 512) kdst[i2] = ksrc[i2];
  }
  __syncthreads();

  const float bav = ba[0];

  // ---- stage 1: scores e[i][j] ----
  {
    const int w    = tid >> 6;          // wave id: j-stride 8
    const int lane = tid & 63;
    const int g    = lane >> 3;         // i = i0 + g
    const int uc   = (lane & 7) * 8;    // 8-u chunk per lane
    float qv[8], wv[8];
    #pragma unroll
    for (int s = 0; s < 8; ++s) qv[s] = qpb[g * UU + uc + s];
    {
      float4 wa0 = *(const float4*)(Wa + uc);
      float4 wa1 = *(const float4*)(Wa + uc + 4);
      wv[0] = wa0.x; wv[1] = wa0.y; wv[2] = wa0.z; wv[3] = wa0.w;
      wv[4] = wa1.x; wv[5] = wa1.y; wv[6] = wa1.z; wv[7] = wa1.w;
    }
    const int ig = i0 + g;
    for (int j = w; j < NJ; j += 8) {
      const float* kp = ks + j * UU + uc;
      float s0 = 0.f;
      #pragma unroll
      for (int s = 0; s < 8; ++s) {
        float z = qv[s] + kp[s];
        s0 += tanh_fast(z) * wv[s];
      }
      s0 += __shfl_xor(s0, 1);
      s0 += __shfl_xor(s0, 2);
      s0 += __shfl_xor(s0, 4);
      const int jg = jlo + j;
      const bool inband = (jg >= ig - HW) && (jg < ig + HW);
      if ((lane & 7) == 0) at[j * 8 + g] = inband ? (s0 + bav) : -1e30f;
    }
  }
  __syncthreads();

  // ---- stage 2: softmax per row over j (one wave per row) ----
  {
    const int row = tid >> 6;   // 0..7
    const int l   = tid & 63;
    float v0 = (l      < NJ) ? at[(l     ) * 8 + row] : -1e30f;
    float v1 = (l + 64 < NJ) ? at[(l + 64) * 8 + row] : -1e30f;
    float m = fmaxf(v0, v1);
    #pragma unroll
    for (int off = 32; off >= 1; off >>= 1) m = fmaxf(m, __shfl_xor(m, off));
    float e0 = __expf(v0 - m);
    float e1 = __expf(v1 - m);
    float ssum = e0 + e1;
    #pragma unroll
    for (int off = 32; off >= 1; off >>= 1) ssum += __shfl_xor(ssum, off);
    float inv = 1.0f / ssum;
    if (l      < NJ) at[(l     ) * 8 + row] = e0 * inv;
    if (l + 64 < NJ) at[(l + 64) * 8 + row] = e1 * inv;
  }
  __syncthreads();

  // ---- stage 3: v = a @ x  (thread owns float2 d-slice, all 8 rows) ----
  {
    float2 vacc[8];
    #pragma unroll
    for (int i = 0; i < 8; ++i) vacc[i] = make_float2(0.f, 0.f);
    const float* xb = x + (size_t)(b * TT + jlo) * DD + 2 * tid;
    #pragma unroll 2
    for (int j = 0; j < NJ; ++j) {
      float2 xv = *(const float2*)(xb + (size_t)j * DD);
      float4 a0 = *(const float4*)(at + j * 8);
      float4 a1 = *(const float4*)(at + j * 8 + 4);
      float av[8] = {a0.x, a0.y, a0.z, a0.w, a1.x, a1.y, a1.z, a1.w};
      #pragma unroll
      for (int i = 0; i < 8; ++i) {
        vacc[i].x = __builtin_fmaf(av[i], xv.x, vacc[i].x);
        vacc[i].y = __builtin_fmaf(av[i], xv.y, vacc[i].y);
      }
    }
    float* ob = out + (size_t)(b * TT + i0) * DD + 2 * tid;
    #pragma unroll
    for (int i = 0; i < 8; ++i) *(float2*)(ob + (size_t)i * DD) = vacc[i];
  }
}

// ---------------------------------------------------------------------------
extern "C" void kernel_launch(void* const* d_in, const int* in_sizes, int n_in,
                              void* d_out, int out_size, void* d_ws, size_t ws_size,
                              hipStream_t stream) {
  const float* x  = (const float*)d_in[0];
  const float* Wt = (const float*)d_in[1];
  const float* Wx = (const float*)d_in[2];
  const float* bh = (const float*)d_in[3];
  const float* Wa = (const float*)d_in[4];
  const float* ba = (const float*)d_in[5];
  float* out = (float*)d_out;

  float* q = (float*)d_ws;                       // [4096, 64] fp32, 1 MB
  float* k = q + (size_t)BB * TT * UU;           // [4096, 64] fp32, 1 MB
  u16* Wht = (u16*)(k + (size_t)BB * TT * UU);   // [128, 1024] bf16, 256 KB
  u16* Wlt = Wht + (size_t)128 * DD;             // [128, 1024] bf16, 256 KB

  wprep_kernel<<<dim3(128), dim3(128), 0, stream>>>(Wt, Wx, Wht, Wlt);
  proj_mfma_kernel<<<dim3((BB * TT) / PROWS), dim3(512), 0, stream>>>(x, Wht, Wlt, q, k);
  band_kernel<<<dim3((BB * TT) / 8), dim3(512), 0, stream>>>(x, q, k, bh, Wa, ba, out);
}

// Round 2
// 117.089 us; speedup vs baseline: 1.0334x; 1.0247x over previous
//
#include <hip/hip_runtime.h>

#define BB 4
#define TT 1024
#define DD 1024
#define UU 64
#define HW 32   // WIDTH/2

typedef unsigned short u16;
typedef __attribute__((ext_vector_type(4))) unsigned short u16x4;
typedef __attribute__((ext_vector_type(8))) unsigned short u16x8;
typedef __attribute__((ext_vector_type(8))) short bf16x8;   // raw bf16 bit patterns
typedef __attribute__((ext_vector_type(4))) float f32x4;

// round-to-nearest-even fp32 -> bf16 (inputs are finite randn; no NaN handling)
__device__ __forceinline__ u16 bf16_rne(float f) {
  unsigned b = __builtin_bit_cast(unsigned, f);
  b += 0x7FFFu + ((b >> 16) & 1u);
  return (u16)(b >> 16);
}
__device__ __forceinline__ float bf16_tof(u16 h) {
  return __builtin_bit_cast(float, ((unsigned)h) << 16);
}

// ---------------------------------------------------------------------------
// wprep v2: W = [Wt | Wx] fp32 [1024 d][64 u] -> transposed bf16 hi/lo
//           Wht/Wlt [128 u][1024 k]. Coalesced: stage a 128d x 64u fp32 tile
//           in LDS (row reads), transpose out of LDS (padded stride 65 ->
//           4-way max bank aliasing), write k-contiguous u16x8 rows.
// ---------------------------------------------------------------------------
#define WLD 65
__global__ __launch_bounds__(256) void wprep_kernel(
    const float* __restrict__ Wt, const float* __restrict__ Wx,
    u16* __restrict__ Wht, u16* __restrict__ Wlt)
{
  __shared__ float ws[128 * WLD];          // 33 KB
  const int tid = threadIdx.x;
  const int d0  = blockIdx.x * 128;
  const float* __restrict__ src = blockIdx.y ? Wx : Wt;

  for (int i = tid; i < 2048; i += 256) {  // 2048 float4 = 128 rows x 16
    int r  = i >> 4;
    int c4 = (i & 15) << 2;
    float4 v = *(const float4*)(src + (size_t)(d0 + r) * UU + c4);
    float* w = ws + r * WLD + c4;
    w[0] = v.x; w[1] = v.y; w[2] = v.z; w[3] = v.w;
  }
  __syncthreads();

  for (int it = tid; it < 1024; it += 256) {   // 64 u x 16 d-octets
    int u = it >> 4, oct = it & 15;
    u16x8 h, l;
    #pragma unroll
    for (int j = 0; j < 8; ++j) {
      float v = ws[(8 * oct + j) * WLD + u];
      u16 hh = bf16_rne(v);
      h[j] = hh;
      l[j] = bf16_rne(v - bf16_tof(hh));       // exact residual (Sterbenz)
    }
    size_t off = (size_t)(blockIdx.y * UU + u) * DD + d0 + 8 * oct;
    *(u16x8*)(Wht + off) = h;
    *(u16x8*)(Wlt + off) = l;
  }
}

// ---------------------------------------------------------------------------
// proj via bf16-split MFMA: UNCHANGED from R1 (verified ~7 us; absmax 0.0039).
// q|k [4096][64] = X[4096][1024] @ [Wt|Wx][1024][128], 4-term bf16 split.
// ---------------------------------------------------------------------------
#define PROWS 16
#define XLD (DD + 8)    // 1032 bf16 row stride: 2064 B -> 2-way max aliasing

__global__ __launch_bounds__(512) void proj_mfma_kernel(
    const float* __restrict__ x, const u16* __restrict__ Wht,
    const u16* __restrict__ Wlt, float* __restrict__ qo, float* __restrict__ ko)
{
  __shared__ __align__(16) u16 Xh[PROWS][XLD];   // 33 KB
  __shared__ __align__(16) u16 Xl[PROWS][XLD];   // 33 KB

  const int tid  = threadIdx.x;
  const int row0 = blockIdx.x * PROWS;

  {
    const float4* src = (const float4*)(x + (size_t)row0 * DD);
    #pragma unroll
    for (int i = 0; i < 8; ++i) {
      int idx4 = tid + 512 * i;
      int r    = idx4 >> 8;
      int k4   = (idx4 & 255) << 2;
      float4 v = src[idx4];
      float vv[4] = {v.x, v.y, v.z, v.w};
      u16x4 hv, lv;
      #pragma unroll
      for (int j = 0; j < 4; ++j) {
        u16 hh = bf16_rne(vv[j]);
        float lf = vv[j] - bf16_tof(hh);
        hv[j] = hh;
        lv[j] = bf16_rne(lf);
      }
      *(u16x4*)&Xh[r][k4] = hv;
      *(u16x4*)&Xl[r][k4] = lv;
    }
  }
  __syncthreads();

  const int lane = tid & 63;
  const int wv   = tid >> 6;
  const int arow = lane & 15;
  const int g    = lane >> 4;
  const int u0   = wv * 16;

  const u16* ah_p = &Xh[arow][8 * g];
  const u16* al_p = &Xl[arow][8 * g];
  const u16* bh_p = Wht + (size_t)(u0 + arow) * DD + 8 * g;
  const u16* bl_p = Wlt + (size_t)(u0 + arow) * DD + 8 * g;

  f32x4 acc0 = {0.f, 0.f, 0.f, 0.f};
  f32x4 acc1 = {0.f, 0.f, 0.f, 0.f};
  f32x4 acc2 = {0.f, 0.f, 0.f, 0.f};
  f32x4 acc3 = {0.f, 0.f, 0.f, 0.f};

  #pragma unroll 8
  for (int ks = 0; ks < 32; ++ks) {
    bf16x8 ah = *(const bf16x8*)(ah_p + 32 * ks);
    bf16x8 al = *(const bf16x8*)(al_p + 32 * ks);
    bf16x8 bh = *(const bf16x8*)(bh_p + 32 * ks);
    bf16x8 bl = *(const bf16x8*)(bl_p + 32 * ks);
    acc0 = __builtin_amdgcn_mfma_f32_16x16x32_bf16(ah, bh, acc0, 0, 0, 0);
    acc1 = __builtin_amdgcn_mfma_f32_16x16x32_bf16(ah, bl, acc1, 0, 0, 0);
    acc2 = __builtin_amdgcn_mfma_f32_16x16x32_bf16(al, bh, acc2, 0, 0, 0);
    acc3 = __builtin_amdgcn_mfma_f32_16x16x32_bf16(al, bl, acc3, 0, 0, 0);
  }

  const int col = u0 + arow;
  float* dst = (col < UU) ? (qo + col) : (ko + (col - UU));
  #pragma unroll
  for (int r = 0; r < 4; ++r) {
    dst[(size_t)(row0 + 4 * g + r) * UU] = acc0[r] + acc1[r] + acc2[r] + acc3[r];
  }
}

// ---------------------------------------------------------------------------
// band v3: exp-product trick. tanh(q+k+bh) = (1-t)/(1+t), t = Eq*Ek with
// Eq = e^{-2(q+bh)}, Ek = e^{-2k} precomputed during staging (4.5K exps/block
// instead of 36K). Per-element body: mul, add, rcp, sub, mul, fma (1 trans
// vs 2). Range: |z| <~ 7 -> t in [7e-13, 1.4e12], no overflow, no NaN.
// Stages 2/3 byte-identical to the 118.8-us baseline.
// ---------------------------------------------------------------------------
__global__ __launch_bounds__(512) void band_kernel(
    const float* __restrict__ x,  const float* __restrict__ qi,
    const float* __restrict__ ki, const float* __restrict__ bh,
    const float* __restrict__ Wa, const float* __restrict__ ba,
    float* __restrict__ out)
{
  __shared__ __align__(16) float eq[8 * UU];     // e^{-2(q+bh)}
  __shared__ __align__(16) float ek[72 * UU];    // e^{-2k}, 18 KB
  __shared__ __align__(16) float at[72 * 8];     // scores / weights, [j][i]

  const int tid  = threadIdx.x;
  const int bid  = blockIdx.x;
  const int tile = (bid & 7) * 64 + (bid >> 3);  // XCD-locality swizzle
  const int b    = tile >> 7;
  const int i0   = (tile & 127) * 8;

  const int jlo = max(0, i0 - HW);
  const int jhi = min(TT, i0 + 8 - 1 + HW);      // exclusive
  const int NJ  = jhi - jlo;                     // 39..71

  // ---- stage Eq, Ek ----
  {
    if (tid < 128) {
      float4 qv = ((const float4*)(qi + (size_t)(b * TT + i0) * UU))[tid];
      float4 bv = ((const float4*)bh)[tid & 15];
      float4 ev;
      ev.x = __expf(-2.0f * (qv.x + bv.x));
      ev.y = __expf(-2.0f * (qv.y + bv.y));
      ev.z = __expf(-2.0f * (qv.z + bv.z));
      ev.w = __expf(-2.0f * (qv.w + bv.w));
      ((float4*)eq)[tid] = ev;
    }
    const float4* ksrc = (const float4*)(ki + (size_t)(b * TT + jlo) * UU);
    const int nk4 = NJ * (UU / 4);
    for (int i2 = tid; i2 < nk4; i2 += 512) {
      float4 kv = ksrc[i2];
      float4 ev;
      ev.x = __expf(-2.0f * kv.x);
      ev.y = __expf(-2.0f * kv.y);
      ev.z = __expf(-2.0f * kv.z);
      ev.w = __expf(-2.0f * kv.w);
      ((float4*)ek)[i2] = ev;
    }
  }
  __syncthreads();

  const float bav = ba[0];

  // ---- stage 1: scores e[i][j] via t = Eq*Ek ----
  {
    const int w    = tid >> 6;          // wave id: j-stride 8
    const int lane = tid & 63;
    const int g    = lane >> 3;         // i = i0 + g
    const int uc   = (lane & 7) * 8;    // 8-u chunk per lane
    float eqv[8], wv[8];
    {
      float4 a0 = *(const float4*)(eq + g * UU + uc);
      float4 a1 = *(const float4*)(eq + g * UU + uc + 4);
      eqv[0] = a0.x; eqv[1] = a0.y; eqv[2] = a0.z; eqv[3] = a0.w;
      eqv[4] = a1.x; eqv[5] = a1.y; eqv[6] = a1.z; eqv[7] = a1.w;
      float4 wa0 = *(const float4*)(Wa + uc);
      float4 wa1 = *(const float4*)(Wa + uc + 4);
      wv[0] = wa0.x; wv[1] = wa0.y; wv[2] = wa0.z; wv[3] = wa0.w;
      wv[4] = wa1.x; wv[5] = wa1.y; wv[6] = wa1.z; wv[7] = wa1.w;
    }
    const int ig = i0 + g;
    for (int j = w; j < NJ; j += 8) {
      const float* kp = ek + j * UU + uc;
      float4 k0 = *(const float4*)kp;
      float4 k1 = *(const float4*)(kp + 4);
      float ekv[8] = {k0.x, k0.y, k0.z, k0.w, k1.x, k1.y, k1.z, k1.w};
      float s0 = 0.f;
      #pragma unroll
      for (int s = 0; s < 8; ++s) {
        float t  = eqv[s] * ekv[s];
        float th = (1.0f - t) * __builtin_amdgcn_rcpf(1.0f + t);
        s0 = __builtin_fmaf(th, wv[s], s0);
      }
      s0 += __shfl_xor(s0, 1);
      s0 += __shfl_xor(s0, 2);
      s0 += __shfl_xor(s0, 4);
      const int jg = jlo + j;
      const bool inband = (jg >= ig - HW) && (jg < ig + HW);
      if ((lane & 7) == 0) at[j * 8 + g] = inband ? (s0 + bav) : -1e30f;
    }
  }
  __syncthreads();

  // ---- stage 2: softmax per row over j (one wave per row) ----
  {
    const int row = tid >> 6;   // 0..7
    const int l   = tid & 63;
    float v0 = (l      < NJ) ? at[(l     ) * 8 + row] : -1e30f;
    float v1 = (l + 64 < NJ) ? at[(l + 64) * 8 + row] : -1e30f;
    float m = fmaxf(v0, v1);
    #pragma unroll
    for (int off = 32; off >= 1; off >>= 1) m = fmaxf(m, __shfl_xor(m, off));
    float e0 = __expf(v0 - m);
    float e1 = __expf(v1 - m);
    float ssum = e0 + e1;
    #pragma unroll
    for (int off = 32; off >= 1; off >>= 1) ssum += __shfl_xor(ssum, off);
    float inv = 1.0f / ssum;
    if (l      < NJ) at[(l     ) * 8 + row] = e0 * inv;
    if (l + 64 < NJ) at[(l + 64) * 8 + row] = e1 * inv;
  }
  __syncthreads();

  // ---- stage 3: v = a @ x  (thread owns float2 d-slice, all 8 rows) ----
  {
    float2 vacc[8];
    #pragma unroll
    for (int i = 0; i < 8; ++i) vacc[i] = make_float2(0.f, 0.f);
    const float* xb = x + (size_t)(b * TT + jlo) * DD + 2 * tid;
    #pragma unroll 2
    for (int j = 0; j < NJ; ++j) {
      float2 xv = *(const float2*)(xb + (size_t)j * DD);
      float4 a0 = *(const float4*)(at + j * 8);
      float4 a1 = *(const float4*)(at + j * 8 + 4);
      float av[8] = {a0.x, a0.y, a0.z, a0.w, a1.x, a1.y, a1.z, a1.w};
      #pragma unroll
      for (int i = 0; i < 8; ++i) {
        vacc[i].x = __builtin_fmaf(av[i], xv.x, vacc[i].x);
        vacc[i].y = __builtin_fmaf(av[i], xv.y, vacc[i].y);
      }
    }
    float* ob = out + (size_t)(b * TT + i0) * DD + 2 * tid;
    #pragma unroll
    for (int i = 0; i < 8; ++i) *(float2*)(ob + (size_t)i * DD) = vacc[i];
  }
}

// ---------------------------------------------------------------------------
extern "C" void kernel_launch(void* const* d_in, const int* in_sizes, int n_in,
                              void* d_out, int out_size, void* d_ws, size_t ws_size,
                              hipStream_t stream) {
  const float* x  = (const float*)d_in[0];
  const float* Wt = (const float*)d_in[1];
  const float* Wx = (const float*)d_in[2];
  const float* bh = (const float*)d_in[3];
  const float* Wa = (const float*)d_in[4];
  const float* ba = (const float*)d_in[5];
  float* out = (float*)d_out;

  float* q = (float*)d_ws;                       // [4096, 64] fp32, 1 MB
  float* k = q + (size_t)BB * TT * UU;           // [4096, 64] fp32, 1 MB
  u16* Wht = (u16*)(k + (size_t)BB * TT * UU);   // [128, 1024] bf16, 256 KB
  u16* Wlt = Wht + (size_t)128 * DD;             // [128, 1024] bf16, 256 KB

  wprep_kernel<<<dim3(8, 2), dim3(256), 0, stream>>>(Wt, Wx, Wht, Wlt);
  proj_mfma_kernel<<<dim3((BB * TT) / PROWS), dim3(512), 0, stream>>>(x, Wht, Wlt, q, k);
  band_kernel<<<dim3((BB * TT) / 8), dim3(512), 0, stream>>>(x, q, k, bh, Wa, ba, out);
}

// Round 3
// 114.633 us; speedup vs baseline: 1.0556x; 1.0214x over previous
//
#include <hip/hip_runtime.h>

#define BB 4
#define TT 1024
#define DD 1024
#define UU 64
#define HW 32   // WIDTH/2

typedef unsigned short u16;
typedef __attribute__((ext_vector_type(4))) unsigned short u16x4;
typedef __attribute__((ext_vector_type(8))) unsigned short u16x8;
typedef __attribute__((ext_vector_type(8))) short bf16x8;   // raw bf16 bit patterns
typedef __attribute__((ext_vector_type(4))) float f32x4;
typedef __attribute__((ext_vector_type(2))) float f32x2;

// round-to-nearest-even fp32 -> bf16 (inputs are finite randn; no NaN handling)
__device__ __forceinline__ u16 bf16_rne(float f) {
  unsigned b = __builtin_bit_cast(unsigned, f);
  b += 0x7FFFu + ((b >> 16) & 1u);
  return (u16)(b >> 16);
}
__device__ __forceinline__ float bf16_tof(u16 h) {
  return __builtin_bit_cast(float, ((unsigned)h) << 16);
}

// ---------------------------------------------------------------------------
// wprep: UNCHANGED from R2. W fp32 -> transposed bf16 hi/lo, coalesced via LDS.
// ---------------------------------------------------------------------------
#define WLD 65
__global__ __launch_bounds__(256) void wprep_kernel(
    const float* __restrict__ Wt, const float* __restrict__ Wx,
    u16* __restrict__ Wht, u16* __restrict__ Wlt)
{
  __shared__ float ws[128 * WLD];          // 33 KB
  const int tid = threadIdx.x;
  const int d0  = blockIdx.x * 128;
  const float* __restrict__ src = blockIdx.y ? Wx : Wt;

  for (int i = tid; i < 2048; i += 256) {  // 2048 float4 = 128 rows x 16
    int r  = i >> 4;
    int c4 = (i & 15) << 2;
    float4 v = *(const float4*)(src + (size_t)(d0 + r) * UU + c4);
    float* w = ws + r * WLD + c4;
    w[0] = v.x; w[1] = v.y; w[2] = v.z; w[3] = v.w;
  }
  __syncthreads();

  for (int it = tid; it < 1024; it += 256) {   // 64 u x 16 d-octets
    int u = it >> 4, oct = it & 15;
    u16x8 h, l;
    #pragma unroll
    for (int j = 0; j < 8; ++j) {
      float v = ws[(8 * oct + j) * WLD + u];
      u16 hh = bf16_rne(v);
      h[j] = hh;
      l[j] = bf16_rne(v - bf16_tof(hh));       // exact residual (Sterbenz)
    }
    size_t off = (size_t)(blockIdx.y * UU + u) * DD + d0 + 8 * oct;
    *(u16x8*)(Wht + off) = h;
    *(u16x8*)(Wlt + off) = l;
  }
}

// ---------------------------------------------------------------------------
// proj via bf16-split MFMA (R1-proven core). NEW epilogue: writes
//   Eq = exp(-2*(q + bh))  and  Ek = exp(-2*k)
// instead of raw q/k, so band needs no exp and no staging (Ek previously
// recomputed ~9x across overlapping band blocks).
// ---------------------------------------------------------------------------
#define PROWS 16
#define XLD (DD + 8)    // 1032 bf16 row stride: 2064 B -> 2-way max aliasing

__global__ __launch_bounds__(512) void proj_mfma_kernel(
    const float* __restrict__ x, const u16* __restrict__ Wht,
    const u16* __restrict__ Wlt, const float* __restrict__ bh,
    float* __restrict__ qo, float* __restrict__ ko)
{
  __shared__ __align__(16) u16 Xh[PROWS][XLD];   // 33 KB
  __shared__ __align__(16) u16 Xl[PROWS][XLD];   // 33 KB

  const int tid  = threadIdx.x;
  const int row0 = blockIdx.x * PROWS;

  {
    const float4* src = (const float4*)(x + (size_t)row0 * DD);
    #pragma unroll
    for (int i = 0; i < 8; ++i) {
      int idx4 = tid + 512 * i;
      int r    = idx4 >> 8;
      int k4   = (idx4 & 255) << 2;
      float4 v = src[idx4];
      float vv[4] = {v.x, v.y, v.z, v.w};
      u16x4 hv, lv;
      #pragma unroll
      for (int j = 0; j < 4; ++j) {
        u16 hh = bf16_rne(vv[j]);
        float lf = vv[j] - bf16_tof(hh);
        hv[j] = hh;
        lv[j] = bf16_rne(lf);
      }
      *(u16x4*)&Xh[r][k4] = hv;
      *(u16x4*)&Xl[r][k4] = lv;
    }
  }
  __syncthreads();

  const int lane = tid & 63;
  const int wv   = tid >> 6;
  const int arow = lane & 15;
  const int g    = lane >> 4;
  const int u0   = wv * 16;

  const u16* ah_p = &Xh[arow][8 * g];
  const u16* al_p = &Xl[arow][8 * g];
  const u16* bh_p = Wht + (size_t)(u0 + arow) * DD + 8 * g;
  const u16* bl_p = Wlt + (size_t)(u0 + arow) * DD + 8 * g;

  f32x4 acc0 = {0.f, 0.f, 0.f, 0.f};
  f32x4 acc1 = {0.f, 0.f, 0.f, 0.f};
  f32x4 acc2 = {0.f, 0.f, 0.f, 0.f};
  f32x4 acc3 = {0.f, 0.f, 0.f, 0.f};

  #pragma unroll 8
  for (int ks = 0; ks < 32; ++ks) {
    bf16x8 ah = *(const bf16x8*)(ah_p + 32 * ks);
    bf16x8 al = *(const bf16x8*)(al_p + 32 * ks);
    bf16x8 bhv = *(const bf16x8*)(bh_p + 32 * ks);
    bf16x8 blv = *(const bf16x8*)(bl_p + 32 * ks);
    acc0 = __builtin_amdgcn_mfma_f32_16x16x32_bf16(ah, bhv, acc0, 0, 0, 0);
    acc1 = __builtin_amdgcn_mfma_f32_16x16x32_bf16(ah, blv, acc1, 0, 0, 0);
    acc2 = __builtin_amdgcn_mfma_f32_16x16x32_bf16(al, bhv, acc2, 0, 0, 0);
    acc3 = __builtin_amdgcn_mfma_f32_16x16x32_bf16(al, blv, acc3, 0, 0, 0);
  }

  // D: lane l, reg r -> row 4*g + r, col u0 + arow; cols 0-63 -> Eq, 64-127 -> Ek
  const int col  = u0 + arow;
  const float bias = (col < UU) ? bh[col] : 0.0f;
  float* dst = (col < UU) ? (qo + col) : (ko + (col - UU));
  #pragma unroll
  for (int r = 0; r < 4; ++r) {
    float v = acc0[r] + acc1[r] + acc2[r] + acc3[r];
    dst[(size_t)(row0 + 4 * g + r) * UU] = __expf(-2.0f * (v + bias));
  }
}

// ---------------------------------------------------------------------------
// band v4: zero staging. Stage 1 reads Eq/Ek straight from global (each Ek
// row is consumed exactly once per block -> LDS staging was a pure extra
// round-trip + barrier). tanh(q+k+bh) = (1-t)/(1+t), t = Eq*Ek.
// Stage 3 on f32x2 ext-vectors -> v_pk_fma_f32 (halves VALU issue), unroll 4
// to keep >=4 x-loads in flight. Stage 2 unchanged. 2 barriers (was 3).
// ---------------------------------------------------------------------------
__global__ __launch_bounds__(512) void band_kernel(
    const float* __restrict__ x,  const float* __restrict__ eqg,
    const float* __restrict__ ekg, const float* __restrict__ Wa,
    const float* __restrict__ ba, float* __restrict__ out)
{
  __shared__ __align__(16) float at[72 * 8];     // scores / weights, [j][i]

  const int tid  = threadIdx.x;
  const int bid  = blockIdx.x;
  const int tile = (bid & 7) * 64 + (bid >> 3);  // XCD-locality swizzle
  const int b    = tile >> 7;
  const int i0   = (tile & 127) * 8;

  const int jlo = max(0, i0 - HW);
  const int jhi = min(TT, i0 + 8 - 1 + HW);      // exclusive
  const int NJ  = jhi - jlo;                     // 39..71

  const float bav = ba[0];

  // ---- stage 1: scores e[i][j] via t = Eq*Ek (direct global reads) ----
  {
    const int w    = tid >> 6;          // wave id: j-stride 8
    const int lane = tid & 63;
    const int g    = lane >> 3;         // i = i0 + g
    const int uc   = (lane & 7) * 8;    // 8-u chunk per lane
    float eqv[8], wv[8];
    {
      const float* qp = eqg + (size_t)(b * TT + i0 + g) * UU + uc;
      float4 a0 = *(const float4*)qp;
      float4 a1 = *(const float4*)(qp + 4);
      eqv[0] = a0.x; eqv[1] = a0.y; eqv[2] = a0.z; eqv[3] = a0.w;
      eqv[4] = a1.x; eqv[5] = a1.y; eqv[6] = a1.z; eqv[7] = a1.w;
      float4 wa0 = *(const float4*)(Wa + uc);
      float4 wa1 = *(const float4*)(Wa + uc + 4);
      wv[0] = wa0.x; wv[1] = wa0.y; wv[2] = wa0.z; wv[3] = wa0.w;
      wv[4] = wa1.x; wv[5] = wa1.y; wv[6] = wa1.z; wv[7] = wa1.w;
    }
    const int ig = i0 + g;
    const float* kbase = ekg + (size_t)(b * TT + jlo) * UU + uc;
    for (int j = w; j < NJ; j += 8) {
      const float* kp = kbase + (size_t)j * UU;
      float4 k0 = *(const float4*)kp;
      float4 k1 = *(const float4*)(kp + 4);
      float ekv[8] = {k0.x, k0.y, k0.z, k0.w, k1.x, k1.y, k1.z, k1.w};
      float s0 = 0.f;
      #pragma unroll
      for (int s = 0; s < 8; ++s) {
        float t  = eqv[s] * ekv[s];
        float th = (1.0f - t) * __builtin_amdgcn_rcpf(1.0f + t);
        s0 = __builtin_fmaf(th, wv[s], s0);
      }
      s0 += __shfl_xor(s0, 1);
      s0 += __shfl_xor(s0, 2);
      s0 += __shfl_xor(s0, 4);
      const int jg = jlo + j;
      const bool inband = (jg >= ig - HW) && (jg < ig + HW);
      if ((lane & 7) == 0) at[j * 8 + g] = inband ? (s0 + bav) : -1e30f;
    }
  }
  __syncthreads();

  // ---- stage 2: softmax per row over j (one wave per row) ----
  {
    const int row = tid >> 6;   // 0..7
    const int l   = tid & 63;
    float v0 = (l      < NJ) ? at[(l     ) * 8 + row] : -1e30f;
    float v1 = (l + 64 < NJ) ? at[(l + 64) * 8 + row] : -1e30f;
    float m = fmaxf(v0, v1);
    #pragma unroll
    for (int off = 32; off >= 1; off >>= 1) m = fmaxf(m, __shfl_xor(m, off));
    float e0 = __expf(v0 - m);
    float e1 = __expf(v1 - m);
    float ssum = e0 + e1;
    #pragma unroll
    for (int off = 32; off >= 1; off >>= 1) ssum += __shfl_xor(ssum, off);
    float inv = 1.0f / ssum;
    if (l      < NJ) at[(l     ) * 8 + row] = e0 * inv;
    if (l + 64 < NJ) at[(l + 64) * 8 + row] = e1 * inv;
  }
  __syncthreads();

  // ---- stage 3: v = a @ x  (f32x2 slice -> v_pk_fma_f32, unroll 4) ----
  {
    const f32x2 z = {0.f, 0.f};
    f32x2 vacc[8];
    #pragma unroll
    for (int i = 0; i < 8; ++i) vacc[i] = z;
    const float* xb = x + (size_t)(b * TT + jlo) * DD + 2 * tid;
    #pragma unroll 4
    for (int j = 0; j < NJ; ++j) {
      f32x2 xv = *(const f32x2*)(xb + (size_t)j * DD);
      float4 a0 = *(const float4*)(at + j * 8);
      float4 a1 = *(const float4*)(at + j * 8 + 4);
      float av[8] = {a0.x, a0.y, a0.z, a0.w, a1.x, a1.y, a1.z, a1.w};
      #pragma unroll
      for (int i = 0; i < 8; ++i) {
        f32x2 s = {av[i], av[i]};
        vacc[i] = s * xv + vacc[i];     // -ffp-contract=fast -> v_pk_fma_f32
      }
    }
    float* ob = out + (size_t)(b * TT + i0) * DD + 2 * tid;
    #pragma unroll
    for (int i = 0; i < 8; ++i) *(f32x2*)(ob + (size_t)i * DD) = vacc[i];
  }
}

// ---------------------------------------------------------------------------
extern "C" void kernel_launch(void* const* d_in, const int* in_sizes, int n_in,
                              void* d_out, int out_size, void* d_ws, size_t ws_size,
                              hipStream_t stream) {
  const float* x  = (const float*)d_in[0];
  const float* Wt = (const float*)d_in[1];
  const float* Wx = (const float*)d_in[2];
  const float* bh = (const float*)d_in[3];
  const float* Wa = (const float*)d_in[4];
  const float* ba = (const float*)d_in[5];
  float* out = (float*)d_out;

  float* q = (float*)d_ws;                       // Eq [4096, 64] fp32, 1 MB
  float* k = q + (size_t)BB * TT * UU;           // Ek [4096, 64] fp32, 1 MB
  u16* Wht = (u16*)(k + (size_t)BB * TT * UU);   // [128, 1024] bf16, 256 KB
  u16* Wlt = Wht + (size_t)128 * DD;             // [128, 1024] bf16, 256 KB

  wprep_kernel<<<dim3(8, 2), dim3(256), 0, stream>>>(Wt, Wx, Wht, Wlt);
  proj_mfma_kernel<<<dim3((BB * TT) / PROWS), dim3(512), 0, stream>>>(x, Wht, Wlt, bh, q, k);
  band_kernel<<<dim3((BB * TT) / 8), dim3(512), 0, stream>>>(x, q, k, Wa, ba, out);
}